// Round 5
// baseline (601.830 us; speedup 1.0000x reference)
//
#include <hip/hip_runtime.h>
#include <hip/hip_bf16.h>
#include <hip/hip_fp16.h>
#include <cstdint>
#include <cstddef>

#define NTOK 16384
#define HD   1024
#define CD   256
#define NE   16
#define RD   128
#define MAXBLK 528          // upper bound on 64-token blocks over all experts
#define EGRID  2304         // ceil(4*MAXBLK / 256) * 256

typedef __attribute__((ext_vector_type(8))) short bf16x8;
typedef __attribute__((ext_vector_type(4))) float f32x4;
typedef unsigned short u16;
typedef unsigned int u32;

__device__ __forceinline__ u16 f2bf(float f) {
    u32 u = __float_as_uint(f);
    u32 r = (u + 0x7FFFu + ((u >> 16) & 1u)) >> 16;   // RNE
    return (u16)r;
}

__device__ __forceinline__ void gload16(const void* g, void* lds) {
    __builtin_amdgcn_global_load_lds((const __attribute__((address_space(1))) void*)g,
                                     (__attribute__((address_space(3))) void*)lds,
                                     16, 0, 0);
}

__device__ __forceinline__ float wredsum(float v) {
#pragma unroll
    for (int m = 32; m >= 1; m >>= 1) v += __shfl_xor(v, m, 64);
    return v;
}

// ---------------- K1: normalize centroids ----------------
__global__ __launch_bounds__(64) void centroid_norm_kernel(
    const float* __restrict__ cen, float* __restrict__ cn, float* __restrict__ sncn)
{
    int e = blockIdx.x, l = threadIdx.x;
    float4 c = *(const float4*)&cen[e * CD + l * 4];
    float ss = wredsum(c.x * c.x + c.y * c.y + c.z * c.z + c.w * c.w);
    float den = fmaxf(sqrtf(ss), 1e-8f);
    float4 n;
    n.x = c.x / den; n.y = c.y / den; n.z = c.z / den; n.w = c.w / den;
    *(float4*)&cn[e * CD + l * 4] = n;
    float s2 = wredsum(n.x * n.x + n.y * n.y + n.z * n.z + n.w * n.w);
    if (l == 0) sncn[e] = s2;
}

// ---------------- K2: distilled = gelu(x @ Wd + bd), fp32, stored TRANSPOSED dT[C][N] ----------------
__global__ __launch_bounds__(256, 4) void router_gemm_kernel(
    const float* __restrict__ x, const float* __restrict__ Wd,
    const float* __restrict__ bd, float* __restrict__ dT)
{
    __shared__ float lA[16][128];
    __shared__ float lB[16][64];
    int tid = threadIdx.x;
    int rb = (blockIdx.x >> 2) * 128;
    int cb = (blockIdx.x & 3) * 64;
    int tx = tid & 15, ty = tid >> 4;
    int arow = tid >> 1, akq = (tid & 1) * 8;
    int bk = tid >> 4, bc = (tid & 15) * 4;
    float acc[8][4];
#pragma unroll
    for (int i = 0; i < 8; ++i)
#pragma unroll
        for (int j = 0; j < 4; ++j) acc[i][j] = 0.f;

    for (int k0 = 0; k0 < HD; k0 += 16) {
        float4 a0 = *(const float4*)&x[(size_t)(rb + arow) * HD + k0 + akq];
        float4 a1 = *(const float4*)&x[(size_t)(rb + arow) * HD + k0 + akq + 4];
        float4 bv = *(const float4*)&Wd[(size_t)(k0 + bk) * CD + cb + bc];
        __syncthreads();
        lA[akq + 0][arow] = a0.x; lA[akq + 1][arow] = a0.y;
        lA[akq + 2][arow] = a0.z; lA[akq + 3][arow] = a0.w;
        lA[akq + 4][arow] = a1.x; lA[akq + 5][arow] = a1.y;
        lA[akq + 6][arow] = a1.z; lA[akq + 7][arow] = a1.w;
        *(float4*)&lB[bk][bc] = bv;
        __syncthreads();
#pragma unroll
        for (int kk = 0; kk < 16; ++kk) {
            float4 va0 = *(const float4*)&lA[kk][ty * 8];
            float4 va1 = *(const float4*)&lA[kk][ty * 8 + 4];
            float4 vb  = *(const float4*)&lB[kk][tx * 4];
            float ar[8] = {va0.x, va0.y, va0.z, va0.w, va1.x, va1.y, va1.z, va1.w};
            float br[4] = {vb.x, vb.y, vb.z, vb.w};
#pragma unroll
            for (int i = 0; i < 8; ++i)
#pragma unroll
                for (int j = 0; j < 4; ++j) acc[i][j] = fmaf(ar[i], br[j], acc[i][j]);
        }
    }
#pragma unroll
    for (int j = 0; j < 4; ++j) {
        int c = cb + tx * 4 + j;
        float b = bd[c];
        float g[8];
#pragma unroll
        for (int i = 0; i < 8; ++i) {
            float v = acc[i][j] + b;
            g[i] = 0.5f * v * (1.f + erff(v * 0.70710678118654752f));
        }
        float4 w0 = {g[0], g[1], g[2], g[3]};
        float4 w1 = {g[4], g[5], g[6], g[7]};
        *(float4*)&dT[(size_t)c * NTOK + rb + ty * 8] = w0;
        *(float4*)&dT[(size_t)c * NTOK + rb + ty * 8 + 4] = w1;
    }
}

// ---------------- K3: router score — lane-local dots, no shuffles ----------------
__global__ __launch_bounds__(256) void router_score_kernel(
    const float* __restrict__ dT, const float* __restrict__ cn,
    const float* __restrict__ sncn, int* __restrict__ top_i,
    float* __restrict__ top_w, int* __restrict__ counts)
{
    __shared__ float lcn[NE][CD];
    __shared__ float sdot[NE][64];
    __shared__ float sss[64];
    __shared__ int hist[NE];
    int tid = threadIdx.x, lane = tid & 63, w = tid >> 6;
    for (int i = tid; i < NE * CD / 4; i += 256)
        ((float4*)&lcn[0][0])[i] = ((const float4*)cn)[i];
    if (tid < NE) hist[tid] = 0;
    __syncthreads();

    int tokbase = blockIdx.x * 64;
    const float* p = dT + tokbase + lane;
    int e0 = w * 4;
    float d0 = 0.f, d1 = 0.f, d2a = 0.f, d3 = 0.f, ss = 0.f;
#pragma unroll 4
    for (int k = 0; k < CD; ++k) {
        float v = p[(size_t)k * NTOK];
        ss = fmaf(v, v, ss);
        d0 = fmaf(v, lcn[e0 + 0][k], d0);
        d1 = fmaf(v, lcn[e0 + 1][k], d1);
        d2a = fmaf(v, lcn[e0 + 2][k], d2a);
        d3 = fmaf(v, lcn[e0 + 3][k], d3);
    }
    sdot[e0 + 0][lane] = d0;
    sdot[e0 + 1][lane] = d1;
    sdot[e0 + 2][lane] = d2a;
    sdot[e0 + 3][lane] = d3;
    if (w == 0) sss[lane] = ss;
    __syncthreads();

    if (tid < 64) {
        int tok = tokbase + tid;
        float ssv = sss[tid];
        float den = fmaxf(sqrtf(ssv), 1e-8f);
        float inv = 1.f / den;
        float sndn = (ssv * inv) * inv;
        float pr[NE];
#pragma unroll
        for (int e = 0; e < NE; ++e) {
            float dotn = sdot[e][tid] * inv;
            float dd2 = sndn + sncn[e] - 2.f * dotn;
            pr[e] = -sqrtf(fmaxf(dd2, 0.f));
        }
        float mx = pr[0];
#pragma unroll
        for (int e = 1; e < NE; ++e) mx = fmaxf(mx, pr[e]);
        float sum = 0.f;
#pragma unroll
        for (int e = 0; e < NE; ++e) { pr[e] = expf(pr[e] - mx); sum += pr[e]; }
        float invs = 1.f / sum;
#pragma unroll
        for (int e = 0; e < NE; ++e) pr[e] *= invs;
        int i1 = 0; float p1 = pr[0];
#pragma unroll
        for (int e = 1; e < NE; ++e) if (pr[e] > p1) { p1 = pr[e]; i1 = e; }
        int i2 = -1; float p2 = -1.f;
#pragma unroll
        for (int e = 0; e < NE; ++e) if (e != i1 && pr[e] > p2) { p2 = pr[e]; i2 = e; }
        top_i[tok * 2 + 0] = i1; top_w[tok * 2 + 0] = p1;
        top_i[tok * 2 + 1] = i2; top_w[tok * 2 + 1] = p2;
        atomicAdd(&hist[i1], 1);
        atomicAdd(&hist[i2], 1);
    }
    __syncthreads();
    if (tid < NE) atomicAdd(&counts[tid], hist[tid]);
}

// ---------------- K4: tiny scan ----------------
__global__ void scan_kernel(const int* __restrict__ counts, int* __restrict__ offsets,
                            int* __restrict__ blkstart, int* __restrict__ cursor)
{
    if (threadIdx.x == 0 && blockIdx.x == 0) {
        int o = 0, b = 0;
        for (int e = 0; e < NE; ++e) {
            offsets[e] = o; blkstart[e] = b; cursor[e] = 0;
            o += counts[e]; b += (counts[e] + 63) >> 6;
        }
        offsets[NE] = o; blkstart[NE] = b;
    }
}

// ---------------- K5: build per-expert token lists ----------------
__global__ __launch_bounds__(256) void build_lists_kernel(
    const int* __restrict__ top_i, const float* __restrict__ top_w,
    const int* __restrict__ offsets, int* __restrict__ cursor,
    int* __restrict__ list_tok, float* __restrict__ list_w)
{
    int t = blockIdx.x * 256 + threadIdx.x;
#pragma unroll
    for (int j = 0; j < 2; ++j) {
        int e = top_i[t * 2 + j];
        int pos = atomicAdd(&cursor[e], 1);
        int idx = offsets[e] + pos;
        list_tok[idx] = t;
        list_w[idx] = top_w[t * 2 + j];
    }
}

// ---------------- K6: fp32 -> bf16 convert ----------------
__global__ __launch_bounds__(256) void cvt_bf16_kernel(
    const float* __restrict__ src, u16* __restrict__ dst, int n4)
{
    int i = blockIdx.x * 256 + threadIdx.x;
    if (i >= n4) return;
    float4 v = *(const float4*)&src[(size_t)i * 4];
    ushort4 o;
    o.x = f2bf(v.x); o.y = f2bf(v.y); o.z = f2bf(v.z); o.w = f2bf(v.w);
    *(ushort4*)&dst[(size_t)i * 4] = o;
}

// ---------------- K7: per-expert transpose + convert: src [K][N] -> dst [N][K] ----------------
__global__ __launch_bounds__(256) void transpose_cvt_kernel(
    const float* __restrict__ src, u16* __restrict__ dst, int K, int N)
{
    __shared__ float t[32][33];
    const float* s = src + (size_t)blockIdx.z * K * N;
    u16* d = dst + (size_t)blockIdx.z * K * N;
    int kb = blockIdx.y * 32, nb = blockIdx.x * 32;
    int r = threadIdx.x >> 3, c4 = (threadIdx.x & 7) * 4;
    float4 v = *(const float4*)&s[(size_t)(kb + r) * N + nb + c4];
    t[r][c4 + 0] = v.x; t[r][c4 + 1] = v.y; t[r][c4 + 2] = v.z; t[r][c4 + 3] = v.w;
    __syncthreads();
    ushort4 o;
    o.x = f2bf(t[c4 + 0][r]); o.y = f2bf(t[c4 + 1][r]);
    o.z = f2bf(t[c4 + 2][r]); o.w = f2bf(t[c4 + 3][r]);
    *(ushort4*)&d[(size_t)(nb + r) * K + kb + c4] = o;
}

// Swizzle: stored[row][s] = logical[row][s ^ ((row>>1)&3)]; stage src slot sl=(lane&3)^((lane>>3)&3);
// frag read slot = hi ^ ((rr>>1)&3).  Pipeline: STAGE(next) -> COMP(cur) -> __syncthreads() (spill-robust).

// ---------------- K8: t = x @ U_e — pipelined ----------------
__global__ __launch_bounds__(256, 3) void tproj_kernel(
    const u16* __restrict__ xbf, const u16* __restrict__ uT,
    const int* __restrict__ list_tok, const int* __restrict__ offsets,
    const int* __restrict__ blkstart, u16* __restrict__ tbf)
{
    __shared__ __align__(16) u16 lds[2 * 6144];
    __shared__ int s_tok[64];
    int mb = blockIdx.x;
    int e = 0;
#pragma unroll
    for (int i = 0; i < NE; ++i) if (mb >= blkstart[i + 1]) e = i + 1;
    if (e >= NE) return;
    int mloc = (mb - blkstart[e]) * 64;
    int base = offsets[e] + mloc;
    int cnt = offsets[e + 1] - offsets[e];
    int mv = min(64, cnt - mloc);
    int tid = threadIdx.x, lane = tid & 63, w = tid >> 6;
    if (tid < 64) s_tok[tid] = list_tok[base + (tid < mv ? tid : 0)];
    __syncthreads();
    int lrow = lane >> 2;
    int sl = (lane & 3) ^ ((lane >> 3) & 3);
    int rr = lane & 15, hi = lane >> 4;
    int rslot = hi ^ ((rr >> 1) & 3);
    const u16* uE = uT + (size_t)e * RD * HD;

    const u16* gb[3]; char* lp[3];
#pragma unroll
    for (int i = 0; i < 3; ++i) {
        int idx = w + 4 * i;
        if (idx < 4) {
            gb[i] = xbf + (size_t)s_tok[idx * 16 + lrow] * HD + sl * 8;
            lp[i] = (char*)lds + idx * 1024;
        } else {
            int bi = idx - 4;
            gb[i] = uE + (size_t)(bi * 16 + lrow) * HD + sl * 8;
            lp[i] = (char*)lds + 4096 + bi * 1024;
        }
    }
    const f32x4 zz = {0.f, 0.f, 0.f, 0.f};
    f32x4 acc[4][2];
#pragma unroll
    for (int im = 0; im < 4; ++im)
#pragma unroll
        for (int in = 0; in < 2; ++in) acc[im][in] = zz;

    auto STAGE = [&](int buf, int t) {
#pragma unroll
        for (int i = 0; i < 3; ++i) gload16(gb[i] + t * 32, lp[i] + buf * 12288);
    };
    auto COMP = [&](int buf, f32x4 (&a)[4][2]) {
        const u16* LA = lds + buf * 6144;
        const u16* LB = LA + 2048;
        bf16x8 af[4], bfv[2];
#pragma unroll
        for (int im = 0; im < 4; ++im) af[im] = *(const bf16x8*)&LA[(im * 16 + rr) * 32 + rslot * 8];
#pragma unroll
        for (int in = 0; in < 2; ++in) bfv[in] = *(const bf16x8*)&LB[(w * 32 + in * 16 + rr) * 32 + rslot * 8];
#pragma unroll
        for (int im = 0; im < 4; ++im)
#pragma unroll
            for (int in = 0; in < 2; ++in)
                a[im][in] = __builtin_amdgcn_mfma_f32_16x16x32_bf16(af[im], bfv[in], a[im][in], 0, 0, 0);
    };

    STAGE(0, 0);
    __syncthreads();
    for (int t = 0; t < 31; ++t) {
        STAGE((t + 1) & 1, t + 1);
        COMP(t & 1, acc);
        __syncthreads();
    }
    COMP(1, acc);

#pragma unroll
    for (int im = 0; im < 4; ++im)
#pragma unroll
        for (int in = 0; in < 2; ++in)
#pragma unroll
            for (int j = 0; j < 4; ++j) {
                int r = im * 16 + hi * 4 + j;
                if (r < mv) {
                    int c = w * 32 + in * 16 + rr;
                    tbf[(size_t)(base + r) * RD + c] = f2bf(acc[im][in][j]);
                }
            }
}

// ---------------- K9: gate GEMM (N=256 tile) + low-rank trans + highway epilogue ----------------
// Dispatch->logical remap: runs of 32 consecutive logical blocks (same e,ct Wg slice) land on
// one XCD (assuming dispatch%8 -> XCD round-robin): l = (d>>8)*256 + (d&7)*32 + ((d&255)>>3).
__global__ __launch_bounds__(256, 3) void expert_kernel(
    const u16* __restrict__ xbf, const u16* __restrict__ wgT,
    const u16* __restrict__ vT, const u16* __restrict__ tbf,
    const float* __restrict__ x, const float* __restrict__ bg,
    const int* __restrict__ list_tok, const float* __restrict__ list_w,
    const int* __restrict__ offsets, const int* __restrict__ blkstart,
    float* __restrict__ out)
{
    __shared__ __align__(16) u16 lds[2 * 10240];   // 2 x (A 4KB + B 16KB)
    __shared__ int s_tok[64];
    __shared__ float s_w[64];
    int d = blockIdx.x;
    int l = (d >> 8) * 256 + (d & 7) * 32 + ((d & 255) >> 3);
    if (l >= 4 * MAXBLK) return;
    int ct = l / MAXBLK;        // 0..3, N-slice of 256 cols
    int mb = l % MAXBLK;
    int e = 0;
#pragma unroll
    for (int i = 0; i < NE; ++i) if (mb >= blkstart[i + 1]) e = i + 1;
    if (e >= NE) return;
    int mloc = (mb - blkstart[e]) * 64;
    int base = offsets[e] + mloc;
    int cnt = offsets[e + 1] - offsets[e];
    int mv = min(64, cnt - mloc);
    int tid = threadIdx.x, lane = tid & 63, w = tid >> 6;
    if (tid < 64) {
        int p = base + (tid < mv ? tid : 0);
        s_tok[tid] = list_tok[p];
        s_w[tid] = (tid < mv) ? list_w[p] : 0.f;
    }
    __syncthreads();
    int lrow = lane >> 2;
    int sl = (lane & 3) ^ ((lane >> 3) & 3);
    int rr = lane & 15, hi = lane >> 4;
    int rslot = hi ^ ((rr >> 1) & 3);

    const u16* wgE = wgT + (size_t)e * HD * HD + (size_t)(ct * 256) * HD;
    const u16* vE  = vT  + (size_t)e * HD * RD + (size_t)(ct * 256) * RD;

    // 5 staging chunks/thread: idx 0..3 -> A rows, idx 4..19 -> B rows (256)
    char* lp[5];
    const u16* gbT[5]; const u16* gbG[5];
#pragma unroll
    for (int i = 0; i < 5; ++i) {
        int idx = w + 4 * i;
        if (idx < 4) {
            lp[i]  = (char*)lds + idx * 1024;
            gbT[i] = tbf + (size_t)(base + idx * 16 + lrow) * RD + sl * 8;
            gbG[i] = xbf + (size_t)s_tok[idx * 16 + lrow] * HD + sl * 8;
        } else {
            int bi = idx - 4;                      // 0..15
            lp[i]  = (char*)lds + 4096 + bi * 1024;
            gbT[i] = vE  + (size_t)(bi * 16 + lrow) * RD + sl * 8;
            gbG[i] = wgE + (size_t)(bi * 16 + lrow) * HD + sl * 8;
        }
    }

    auto STAGE = [&](int buf, int t, const u16* const (&gb)[5]) {
#pragma unroll
        for (int i = 0; i < 5; ++i) gload16(gb[i] + t * 32, lp[i] + buf * 20480);
    };
    auto COMP = [&](int buf, f32x4 (&a)[4][4]) {
        const u16* LA = lds + buf * 10240;
        const u16* LB = LA + 2048;
        bf16x8 af[4], bfv[4];
#pragma unroll
        for (int im = 0; im < 4; ++im) af[im] = *(const bf16x8*)&LA[(im * 16 + rr) * 32 + rslot * 8];
#pragma unroll
        for (int in = 0; in < 4; ++in) bfv[in] = *(const bf16x8*)&LB[(w * 64 + in * 16 + rr) * 32 + rslot * 8];
#pragma unroll
        for (int im = 0; im < 4; ++im)
#pragma unroll
            for (int in = 0; in < 4; ++in)
                a[im][in] = __builtin_amdgcn_mfma_f32_16x16x32_bf16(af[im], bfv[in], a[im][in], 0, 0, 0);
    };

    const f32x4 zz = {0.f, 0.f, 0.f, 0.f};
    float bgv[4];
#pragma unroll
    for (int in = 0; in < 4; ++in)
        bgv[in] = bg[e * HD + ct * 256 + w * 64 + in * 16 + rr];

    // ---- phase 1: gate = x @ Wg_e (32 K-steps) ----
    f32x4 accG[4][4];
#pragma unroll
    for (int im = 0; im < 4; ++im)
#pragma unroll
        for (int in = 0; in < 4; ++in) accG[im][in] = zz;

    STAGE(0, 0, gbG);
    __syncthreads();
    for (int t = 0; t < 32; ++t) {
        if (t < 31) STAGE((t + 1) & 1, t + 1, gbG);
        else        STAGE(0, 0, gbT);       // trans step 0 prefetch under last gate COMP
        COMP(t & 1, accG);
        __syncthreads();
    }

    // sigmoid + pack gate to fp16 (frees accG's AGPRs before accT is live)
    __half2 sgp[4][4][2];
#pragma unroll
    for (int im = 0; im < 4; ++im)
#pragma unroll
        for (int in = 0; in < 4; ++in) {
            float s0 = 1.f / (1.f + __expf(-(accG[im][in][0] + bgv[in])));
            float s1 = 1.f / (1.f + __expf(-(accG[im][in][1] + bgv[in])));
            float s2 = 1.f / (1.f + __expf(-(accG[im][in][2] + bgv[in])));
            float s3 = 1.f / (1.f + __expf(-(accG[im][in][3] + bgv[in])));
            sgp[im][in][0] = __floats2half2_rn(s0, s1);
            sgp[im][in][1] = __floats2half2_rn(s2, s3);
        }

    // ---- phase 2: trans = t @ V_e (4 K-steps over RD=128) ----
    f32x4 accT[4][4];
#pragma unroll
    for (int im = 0; im < 4; ++im)
#pragma unroll
        for (int in = 0; in < 4; ++in) accT[im][in] = zz;

#pragma unroll
    for (int s = 0; s < 4; ++s) {
        if (s < 3) STAGE((s + 1) & 1, s + 1, gbT);
        COMP(s & 1, accT);
        __syncthreads();
    }

    // ---- epilogue ----
#pragma unroll
    for (int im = 0; im < 4; ++im)
#pragma unroll
        for (int j = 0; j < 4; ++j) {
            int r = im * 16 + hi * 4 + j;
            if (r < mv) {
                int tok = s_tok[r];
                float wgt = s_w[r];
                size_t rowoff = (size_t)tok * HD;
#pragma unroll
                for (int in = 0; in < 4; ++in) {
                    int c = ct * 256 + w * 64 + in * 16 + rr;
                    float2 sq = __half22float2(sgp[im][in][j >> 1]);
                    float sg = (j & 1) ? sq.y : sq.x;
                    float tr = accT[im][in][j];
                    float xv = x[rowoff + c];
                    float yv = sg * tr + (1.f - sg) * xv;
                    atomicAdd(&out[rowoff + c], wgt * yv);
                }
            }
        }
}

extern "C" void kernel_launch(void* const* d_in, const int* in_sizes, int n_in,
                              void* d_out, int out_size, void* d_ws, size_t ws_size,
                              hipStream_t stream)
{
    const float* x   = (const float*)d_in[0];
    const float* Wd  = (const float*)d_in[1];
    const float* bd  = (const float*)d_in[2];
    const float* cen = (const float*)d_in[3];
    const float* Wg  = (const float*)d_in[4];
    const float* bg  = (const float*)d_in[5];
    const float* U   = (const float*)d_in[6];
    const float* V   = (const float*)d_in[7];
    float* out = (float*)d_out;

    char* ws = (char*)d_ws;
    size_t off = 0;
    auto alloc = [&](size_t bytes) { size_t o = off; off = (off + bytes + 255) & ~(size_t)255; return o; };
    float* dT        = (float*)(ws + alloc((size_t)NTOK * CD * 4));
    float* cn        = (float*)(ws + alloc((size_t)NE * CD * 4));
    float* sncn      = (float*)(ws + alloc(NE * 4));
    int*   top_i     = (int*)(ws + alloc((size_t)NTOK * 2 * 4));
    float* top_w     = (float*)(ws + alloc((size_t)NTOK * 2 * 4));
    int*   counts    = (int*)(ws + alloc(NE * 4));
    int*   offsets   = (int*)(ws + alloc((NE + 1) * 4));
    int*   blkstart  = (int*)(ws + alloc((NE + 1) * 4));
    int*   cursor    = (int*)(ws + alloc(NE * 4));
    int*   list_tok  = (int*)(ws + alloc((size_t)NTOK * 2 * 4));
    float* list_w    = (float*)(ws + alloc((size_t)NTOK * 2 * 4));
    u16*   xbf       = (u16*)(ws + alloc((size_t)NTOK * HD * 2));
    u16*   wgT       = (u16*)(ws + alloc((size_t)NE * HD * HD * 2));
    u16*   uT        = (u16*)(ws + alloc((size_t)NE * RD * HD * 2));
    u16*   vT        = (u16*)(ws + alloc((size_t)NE * RD * HD * 2));
    u16*   tbf       = (u16*)(ws + alloc(((size_t)NTOK * 2 + 64) * RD * 2));

    hipMemsetAsync(out, 0, (size_t)out_size * 4, stream);
    hipMemsetAsync(counts, 0, NE * 4, stream);

    centroid_norm_kernel<<<NE, 64, 0, stream>>>(cen, cn, sncn);
    router_gemm_kernel<<<(NTOK / 128) * 4, 256, 0, stream>>>(x, Wd, bd, dT);
    router_score_kernel<<<NTOK / 64, 256, 0, stream>>>(dT, cn, sncn, top_i, top_w, counts);
    scan_kernel<<<1, 64, 0, stream>>>(counts, offsets, blkstart, cursor);
    build_lists_kernel<<<NTOK / 256, 256, 0, stream>>>(top_i, top_w, offsets, cursor, list_tok, list_w);

    cvt_bf16_kernel<<<(NTOK * HD / 4 + 255) / 256, 256, 0, stream>>>(x, xbf, NTOK * HD / 4);
    transpose_cvt_kernel<<<dim3(HD / 32, HD / 32, NE), 256, 0, stream>>>(Wg, wgT, HD, HD);
    transpose_cvt_kernel<<<dim3(RD / 32, HD / 32, NE), 256, 0, stream>>>(U, uT, HD, RD);
    transpose_cvt_kernel<<<dim3(HD / 32, RD / 32, NE), 256, 0, stream>>>(V, vT, RD, HD);

    tproj_kernel<<<MAXBLK, 256, 0, stream>>>(xbf, uT, list_tok, offsets, blkstart, tbf);
    expert_kernel<<<EGRID, 256, 0, stream>>>(xbf, wgT, vT, tbf, x, bg,
                                             list_tok, list_w, offsets, blkstart, out);
}

// Round 6
// 563.371 us; speedup vs baseline: 1.0683x; 1.0683x over previous
//
#include <hip/hip_runtime.h>
#include <hip/hip_bf16.h>
#include <hip/hip_fp16.h>
#include <cstdint>
#include <cstddef>

#define NTOK 16384
#define HD   1024
#define CD   256
#define NE   16
#define RD   128
#define MB2    272          // upper bound on 128-token blocks over all experts
#define LOGB   2176         // MB2 * 8 ct-tiles
#define EGRID  2304         // ceil(LOGB/256)*256  (multiple of 256 -> bijective remap)

typedef __attribute__((ext_vector_type(8))) short bf16x8;
typedef __attribute__((ext_vector_type(4))) float f32x4;
typedef unsigned short u16;
typedef unsigned int u32;

__device__ __forceinline__ u16 f2bf(float f) {
    u32 u = __float_as_uint(f);
    u32 r = (u + 0x7FFFu + ((u >> 16) & 1u)) >> 16;   // RNE
    return (u16)r;
}

__device__ __forceinline__ void gload16(const void* g, void* lds) {
    __builtin_amdgcn_global_load_lds((const __attribute__((address_space(1))) void*)g,
                                     (__attribute__((address_space(3))) void*)lds,
                                     16, 0, 0);
}

__device__ __forceinline__ float wredsum(float v) {
#pragma unroll
    for (int m = 32; m >= 1; m >>= 1) v += __shfl_xor(v, m, 64);
    return v;
}

// ---------------- K1: normalize centroids ----------------
__global__ __launch_bounds__(64) void centroid_norm_kernel(
    const float* __restrict__ cen, float* __restrict__ cn, float* __restrict__ sncn)
{
    int e = blockIdx.x, l = threadIdx.x;
    float4 c = *(const float4*)&cen[e * CD + l * 4];
    float ss = wredsum(c.x * c.x + c.y * c.y + c.z * c.z + c.w * c.w);
    float den = fmaxf(sqrtf(ss), 1e-8f);
    float4 n;
    n.x = c.x / den; n.y = c.y / den; n.z = c.z / den; n.w = c.w / den;
    *(float4*)&cn[e * CD + l * 4] = n;
    float s2 = wredsum(n.x * n.x + n.y * n.y + n.z * n.z + n.w * n.w);
    if (l == 0) sncn[e] = s2;
}

// ---------------- K2: distilled = gelu(x @ Wd + bd), fp32, stored TRANSPOSED dT[C][N] ----------------
__global__ __launch_bounds__(256, 4) void router_gemm_kernel(
    const float* __restrict__ x, const float* __restrict__ Wd,
    const float* __restrict__ bd, float* __restrict__ dT)
{
    __shared__ float lA[16][128];
    __shared__ float lB[16][64];
    int tid = threadIdx.x;
    int rb = (blockIdx.x >> 2) * 128;
    int cb = (blockIdx.x & 3) * 64;
    int tx = tid & 15, ty = tid >> 4;
    int arow = tid >> 1, akq = (tid & 1) * 8;
    int bk = tid >> 4, bc = (tid & 15) * 4;
    float acc[8][4];
#pragma unroll
    for (int i = 0; i < 8; ++i)
#pragma unroll
        for (int j = 0; j < 4; ++j) acc[i][j] = 0.f;

    for (int k0 = 0; k0 < HD; k0 += 16) {
        float4 a0 = *(const float4*)&x[(size_t)(rb + arow) * HD + k0 + akq];
        float4 a1 = *(const float4*)&x[(size_t)(rb + arow) * HD + k0 + akq + 4];
        float4 bv = *(const float4*)&Wd[(size_t)(k0 + bk) * CD + cb + bc];
        __syncthreads();
        lA[akq + 0][arow] = a0.x; lA[akq + 1][arow] = a0.y;
        lA[akq + 2][arow] = a0.z; lA[akq + 3][arow] = a0.w;
        lA[akq + 4][arow] = a1.x; lA[akq + 5][arow] = a1.y;
        lA[akq + 6][arow] = a1.z; lA[akq + 7][arow] = a1.w;
        *(float4*)&lB[bk][bc] = bv;
        __syncthreads();
#pragma unroll
        for (int kk = 0; kk < 16; ++kk) {
            float4 va0 = *(const float4*)&lA[kk][ty * 8];
            float4 va1 = *(const float4*)&lA[kk][ty * 8 + 4];
            float4 vb  = *(const float4*)&lB[kk][tx * 4];
            float ar[8] = {va0.x, va0.y, va0.z, va0.w, va1.x, va1.y, va1.z, va1.w};
            float br[4] = {vb.x, vb.y, vb.z, vb.w};
#pragma unroll
            for (int i = 0; i < 8; ++i)
#pragma unroll
                for (int j = 0; j < 4; ++j) acc[i][j] = fmaf(ar[i], br[j], acc[i][j]);
        }
    }
#pragma unroll
    for (int j = 0; j < 4; ++j) {
        int c = cb + tx * 4 + j;
        float b = bd[c];
        float g[8];
#pragma unroll
        for (int i = 0; i < 8; ++i) {
            float v = acc[i][j] + b;
            g[i] = 0.5f * v * (1.f + erff(v * 0.70710678118654752f));
        }
        float4 w0 = {g[0], g[1], g[2], g[3]};
        float4 w1 = {g[4], g[5], g[6], g[7]};
        *(float4*)&dT[(size_t)c * NTOK + rb + ty * 8] = w0;
        *(float4*)&dT[(size_t)c * NTOK + rb + ty * 8 + 4] = w1;
    }
}

// ---------------- K3: router score — lane-local dots, no shuffles ----------------
__global__ __launch_bounds__(256) void router_score_kernel(
    const float* __restrict__ dT, const float* __restrict__ cn,
    const float* __restrict__ sncn, int* __restrict__ top_i,
    float* __restrict__ top_w, int* __restrict__ counts)
{
    __shared__ float lcn[NE][CD];
    __shared__ float sdot[NE][64];
    __shared__ float sss[64];
    __shared__ int hist[NE];
    int tid = threadIdx.x, lane = tid & 63, w = tid >> 6;
    for (int i = tid; i < NE * CD / 4; i += 256)
        ((float4*)&lcn[0][0])[i] = ((const float4*)cn)[i];
    if (tid < NE) hist[tid] = 0;
    __syncthreads();

    int tokbase = blockIdx.x * 64;
    const float* p = dT + tokbase + lane;
    int e0 = w * 4;
    float d0 = 0.f, d1 = 0.f, d2a = 0.f, d3 = 0.f, ss = 0.f;
#pragma unroll 4
    for (int k = 0; k < CD; ++k) {
        float v = p[(size_t)k * NTOK];
        ss = fmaf(v, v, ss);
        d0 = fmaf(v, lcn[e0 + 0][k], d0);
        d1 = fmaf(v, lcn[e0 + 1][k], d1);
        d2a = fmaf(v, lcn[e0 + 2][k], d2a);
        d3 = fmaf(v, lcn[e0 + 3][k], d3);
    }
    sdot[e0 + 0][lane] = d0;
    sdot[e0 + 1][lane] = d1;
    sdot[e0 + 2][lane] = d2a;
    sdot[e0 + 3][lane] = d3;
    if (w == 0) sss[lane] = ss;
    __syncthreads();

    if (tid < 64) {
        int tok = tokbase + tid;
        float ssv = sss[tid];
        float den = fmaxf(sqrtf(ssv), 1e-8f);
        float inv = 1.f / den;
        float sndn = (ssv * inv) * inv;
        float pr[NE];
#pragma unroll
        for (int e = 0; e < NE; ++e) {
            float dotn = sdot[e][tid] * inv;
            float dd2 = sndn + sncn[e] - 2.f * dotn;
            pr[e] = -sqrtf(fmaxf(dd2, 0.f));
        }
        float mx = pr[0];
#pragma unroll
        for (int e = 1; e < NE; ++e) mx = fmaxf(mx, pr[e]);
        float sum = 0.f;
#pragma unroll
        for (int e = 0; e < NE; ++e) { pr[e] = expf(pr[e] - mx); sum += pr[e]; }
        float invs = 1.f / sum;
#pragma unroll
        for (int e = 0; e < NE; ++e) pr[e] *= invs;
        int i1 = 0; float p1 = pr[0];
#pragma unroll
        for (int e = 1; e < NE; ++e) if (pr[e] > p1) { p1 = pr[e]; i1 = e; }
        int i2 = -1; float p2 = -1.f;
#pragma unroll
        for (int e = 0; e < NE; ++e) if (e != i1 && pr[e] > p2) { p2 = pr[e]; i2 = e; }
        top_i[tok * 2 + 0] = i1; top_w[tok * 2 + 0] = p1;
        top_i[tok * 2 + 1] = i2; top_w[tok * 2 + 1] = p2;
        atomicAdd(&hist[i1], 1);
        atomicAdd(&hist[i2], 1);
    }
    __syncthreads();
    if (tid < NE) atomicAdd(&counts[tid], hist[tid]);
}

// ---------------- K4: tiny scan (128-row blocks) ----------------
__global__ void scan_kernel(const int* __restrict__ counts, int* __restrict__ offsets,
                            int* __restrict__ blkstart, int* __restrict__ cursor)
{
    if (threadIdx.x == 0 && blockIdx.x == 0) {
        int o = 0, b = 0;
        for (int e = 0; e < NE; ++e) {
            offsets[e] = o; blkstart[e] = b; cursor[e] = 0;
            o += counts[e]; b += (counts[e] + 127) >> 7;
        }
        offsets[NE] = o; blkstart[NE] = b;
    }
}

// ---------------- K5: build per-expert token lists ----------------
__global__ __launch_bounds__(256) void build_lists_kernel(
    const int* __restrict__ top_i, const float* __restrict__ top_w,
    const int* __restrict__ offsets, int* __restrict__ cursor,
    int* __restrict__ list_tok, float* __restrict__ list_w)
{
    int t = blockIdx.x * 256 + threadIdx.x;
#pragma unroll
    for (int j = 0; j < 2; ++j) {
        int e = top_i[t * 2 + j];
        int pos = atomicAdd(&cursor[e], 1);
        int idx = offsets[e] + pos;
        list_tok[idx] = t;
        list_w[idx] = top_w[t * 2 + j];
    }
}

// ---------------- K6: fp32 -> bf16 convert ----------------
__global__ __launch_bounds__(256) void cvt_bf16_kernel(
    const float* __restrict__ src, u16* __restrict__ dst, int n4)
{
    int i = blockIdx.x * 256 + threadIdx.x;
    if (i >= n4) return;
    float4 v = *(const float4*)&src[(size_t)i * 4];
    ushort4 o;
    o.x = f2bf(v.x); o.y = f2bf(v.y); o.z = f2bf(v.z); o.w = f2bf(v.w);
    *(ushort4*)&dst[(size_t)i * 4] = o;
}

// ---------------- K7: per-expert transpose + convert: src [K][N] -> dst [N][K] ----------------
__global__ __launch_bounds__(256) void transpose_cvt_kernel(
    const float* __restrict__ src, u16* __restrict__ dst, int K, int N)
{
    __shared__ float t[32][33];
    const float* s = src + (size_t)blockIdx.z * K * N;
    u16* d = dst + (size_t)blockIdx.z * K * N;
    int kb = blockIdx.y * 32, nb = blockIdx.x * 32;
    int r = threadIdx.x >> 3, c4 = (threadIdx.x & 7) * 4;
    float4 v = *(const float4*)&s[(size_t)(kb + r) * N + nb + c4];
    t[r][c4 + 0] = v.x; t[r][c4 + 1] = v.y; t[r][c4 + 2] = v.z; t[r][c4 + 3] = v.w;
    __syncthreads();
    ushort4 o;
    o.x = f2bf(t[c4 + 0][r]); o.y = f2bf(t[c4 + 1][r]);
    o.z = f2bf(t[c4 + 2][r]); o.w = f2bf(t[c4 + 3][r]);
    *(ushort4*)&d[(size_t)(nb + r) * K + kb + c4] = o;
}

// ---- m97 geometry: 128x128 tile, BK=32. Per step: 16 units x 1KB staged (A 8KB + B 8KB),
// 4 gload16/thread, 16 MFMA/wave. Waves 2x2: wr=w>>1 (M-half), wc=w&1 (N-half).
// Swizzle: stored[row][s]=logical[row][s^((row>>1)&3)]; stage slot sl=(lane&3)^((lane>>3)&3);
// read slot rslot=hi^((rr>>1)&3).  Pipeline: STAGE(next)->COMP(cur)->__syncthreads() (spill-robust).

// ---------------- K8: t = x @ U_e — M=128 ----------------
__global__ __launch_bounds__(256, 3) void tproj_kernel(
    const u16* __restrict__ xbf, const u16* __restrict__ uT,
    const int* __restrict__ list_tok, const int* __restrict__ offsets,
    const int* __restrict__ blkstart, u16* __restrict__ tbf)
{
    __shared__ __align__(16) u16 lds[2 * 8192];
    __shared__ int s_tok[128];
    int mb = blockIdx.x;
    int e = 0;
#pragma unroll
    for (int i = 0; i < NE; ++i) if (mb >= blkstart[i + 1]) e = i + 1;
    if (e >= NE) return;
    int mloc = (mb - blkstart[e]) * 128;
    int base = offsets[e] + mloc;
    int cnt = offsets[e + 1] - offsets[e];
    int mv = min(128, cnt - mloc);
    int tid = threadIdx.x, lane = tid & 63, w = tid >> 6;
    if (tid < 128) s_tok[tid] = list_tok[base + (tid < mv ? tid : 0)];
    __syncthreads();
    int lrow = lane >> 2;
    int sl = (lane & 3) ^ ((lane >> 3) & 3);
    int rr = lane & 15, hi = lane >> 4;
    int rslot = hi ^ ((rr >> 1) & 3);
    int wr = w >> 1, wc = w & 1;
    const u16* uE = uT + (size_t)e * RD * HD;

    const u16* gb[4]; char* lp[4];
#pragma unroll
    for (int i = 0; i < 4; ++i) {
        int idx = w + 4 * i;               // 0..15
        if (idx < 8) {
            int row = idx * 16 + lrow;     // 0..127 (token row)
            gb[i] = xbf + (size_t)s_tok[row] * HD + sl * 8;
            lp[i] = (char*)lds + idx * 1024;
        } else {
            int row = (idx - 8) * 16 + lrow;   // U row 0..127
            gb[i] = uE + (size_t)row * HD + sl * 8;
            lp[i] = (char*)lds + 8192 + (idx - 8) * 1024;
        }
    }
    const f32x4 zz = {0.f, 0.f, 0.f, 0.f};
    f32x4 acc[4][4];
#pragma unroll
    for (int im = 0; im < 4; ++im)
#pragma unroll
        for (int in = 0; in < 4; ++in) acc[im][in] = zz;

    auto STAGE = [&](int buf, int t) {
#pragma unroll
        for (int i = 0; i < 4; ++i) gload16(gb[i] + t * 32, lp[i] + buf * 16384);
    };
    auto COMP = [&](int buf, f32x4 (&a)[4][4]) {
        const u16* LA = lds + buf * 8192;
        const u16* LB = LA + 4096;
        bf16x8 af[4], bfv[4];
#pragma unroll
        for (int im = 0; im < 4; ++im) af[im] = *(const bf16x8*)&LA[(wr * 64 + im * 16 + rr) * 32 + rslot * 8];
#pragma unroll
        for (int in = 0; in < 4; ++in) bfv[in] = *(const bf16x8*)&LB[(wc * 64 + in * 16 + rr) * 32 + rslot * 8];
#pragma unroll
        for (int im = 0; im < 4; ++im)
#pragma unroll
            for (int in = 0; in < 4; ++in)
                a[im][in] = __builtin_amdgcn_mfma_f32_16x16x32_bf16(af[im], bfv[in], a[im][in], 0, 0, 0);
    };

    STAGE(0, 0);
    __syncthreads();
    for (int t = 0; t < 31; ++t) {
        STAGE((t + 1) & 1, t + 1);
        COMP(t & 1, acc);
        __syncthreads();
    }
    COMP(1, acc);

#pragma unroll
    for (int im = 0; im < 4; ++im)
#pragma unroll
        for (int in = 0; in < 4; ++in)
#pragma unroll
            for (int j = 0; j < 4; ++j) {
                int r = wr * 64 + im * 16 + hi * 4 + j;
                if (r < mv) {
                    int c = wc * 64 + in * 16 + rr;
                    tbf[(size_t)(base + r) * RD + c] = f2bf(acc[im][in][j]);
                }
            }
}

// ---------------- K9: trans GEMM + gate GEMM + highway epilogue (M=128, N=128) ----------------
// Logical l in [0,LOGB): mb = l>>3, ct = l&7 (ct-minor: neighbors share token A-tiles in L2).
// Dispatch remap keeps 32 consecutive l on one XCD: l=(d>>8)*256+(d&7)*32+((d&255)>>3); EGRID mult of 256.
__global__ __launch_bounds__(256, 3) void expert_kernel(
    const u16* __restrict__ xbf, const u16* __restrict__ wgT,
    const u16* __restrict__ vT, const u16* __restrict__ tbf,
    const float* __restrict__ x, const float* __restrict__ bg,
    const int* __restrict__ list_tok, const float* __restrict__ list_w,
    const int* __restrict__ offsets, const int* __restrict__ blkstart,
    float* __restrict__ out)
{
    __shared__ __align__(16) u16 lds[2 * 8192];    // 32 KB
    __shared__ int s_tok[128];
    __shared__ float s_w[128];
    int d = blockIdx.x;
    int l = (d >> 8) * 256 + (d & 7) * 32 + ((d & 255) >> 3);
    if (l >= LOGB) return;
    int mb = l >> 3, ct = l & 7;
    int e = 0;
#pragma unroll
    for (int i = 0; i < NE; ++i) if (mb >= blkstart[i + 1]) e = i + 1;
    if (e >= NE) return;
    int mloc = (mb - blkstart[e]) * 128;
    int base = offsets[e] + mloc;
    int cnt = offsets[e + 1] - offsets[e];
    int mv = min(128, cnt - mloc);
    int tid = threadIdx.x, lane = tid & 63, w = tid >> 6;
    if (tid < 128) {
        int p = base + (tid < mv ? tid : 0);
        s_tok[tid] = list_tok[p];
        s_w[tid] = (tid < mv) ? list_w[p] : 0.f;
    }
    __syncthreads();
    int lrow = lane >> 2;
    int sl = (lane & 3) ^ ((lane >> 3) & 3);
    int rr = lane & 15, hi = lane >> 4;
    int rslot = hi ^ ((rr >> 1) & 3);
    int wr = w >> 1, wc = w & 1;

    const u16* wgE = wgT + (size_t)e * HD * HD + (size_t)(ct * 128) * HD;
    const u16* vE  = vT  + (size_t)e * HD * RD + (size_t)(ct * 128) * RD;

    char* lp[4];
    const u16* gbT[4]; const u16* gbG[4];
#pragma unroll
    for (int i = 0; i < 4; ++i) {
        int idx = w + 4 * i;               // 0..15
        if (idx < 8) {
            int row = idx * 16 + lrow;     // token row 0..127
            lp[i]  = (char*)lds + idx * 1024;
            gbT[i] = tbf + (size_t)(base + (row < mv ? row : 0)) * RD + sl * 8;
            gbG[i] = xbf + (size_t)s_tok[row] * HD + sl * 8;
        } else {
            int row = (idx - 8) * 16 + lrow;   // weight row 0..127
            lp[i]  = (char*)lds + 8192 + (idx - 8) * 1024;
            gbT[i] = vE  + (size_t)row * RD + sl * 8;
            gbG[i] = wgE + (size_t)row * HD + sl * 8;
        }
    }

    auto STAGE = [&](int buf, int t, const u16* const (&gb)[4]) {
#pragma unroll
        for (int i = 0; i < 4; ++i) gload16(gb[i] + t * 32, lp[i] + buf * 16384);
    };
    auto COMP = [&](int buf, f32x4 (&a)[4][4]) {
        const u16* LA = lds + buf * 8192;
        const u16* LB = LA + 4096;
        bf16x8 af[4], bfv[4];
#pragma unroll
        for (int im = 0; im < 4; ++im) af[im] = *(const bf16x8*)&LA[(wr * 64 + im * 16 + rr) * 32 + rslot * 8];
#pragma unroll
        for (int in = 0; in < 4; ++in) bfv[in] = *(const bf16x8*)&LB[(wc * 64 + in * 16 + rr) * 32 + rslot * 8];
#pragma unroll
        for (int im = 0; im < 4; ++im)
#pragma unroll
            for (int in = 0; in < 4; ++in)
                a[im][in] = __builtin_amdgcn_mfma_f32_16x16x32_bf16(af[im], bfv[in], a[im][in], 0, 0, 0);
    };

    const f32x4 zz = {0.f, 0.f, 0.f, 0.f};
    // ---- phase 1: trans = t @ V_e (4 K-steps over RD=128) ----
    f32x4 accT[4][4];
#pragma unroll
    for (int im = 0; im < 4; ++im)
#pragma unroll
        for (int in = 0; in < 4; ++in) accT[im][in] = zz;

    STAGE(0, 0, gbT);
    __syncthreads();
#pragma unroll
    for (int s = 0; s < 4; ++s) {
        if (s < 3) STAGE((s + 1) & 1, s + 1, gbT);
        else       STAGE(0, 0, gbG);       // gate step 0 prefetch under last trans COMP
        COMP(s & 1, accT);
        __syncthreads();
    }

    // pack trans to fp16 (frees accT before accG goes live)
    __half2 tpk[4][4][2];
#pragma unroll
    for (int im = 0; im < 4; ++im)
#pragma unroll
        for (int in = 0; in < 4; ++in) {
            tpk[im][in][0] = __floats2half2_rn(accT[im][in][0], accT[im][in][1]);
            tpk[im][in][1] = __floats2half2_rn(accT[im][in][2], accT[im][in][3]);
        }

    // ---- phase 2: gate = x @ Wg_e (32 K-steps over HD=1024) ----
    f32x4 accG[4][4];
#pragma unroll
    for (int im = 0; im < 4; ++im)
#pragma unroll
        for (int in = 0; in < 4; ++in) accG[im][in] = zz;

    for (int t = 0; t < 31; ++t) {
        STAGE((t + 1) & 1, t + 1, gbG);
        COMP(t & 1, accG);
        __syncthreads();
    }
    COMP(1, accG);

    // ---- epilogue ----
    float bgv[4];
#pragma unroll
    for (int in = 0; in < 4; ++in)
        bgv[in] = bg[e * HD + ct * 128 + wc * 64 + in * 16 + rr];

#pragma unroll
    for (int im = 0; im < 4; ++im)
#pragma unroll
        for (int j = 0; j < 4; ++j) {
            int r = wr * 64 + im * 16 + hi * 4 + j;
            if (r < mv) {
                int tok = s_tok[r];
                float wgt = s_w[r];
                size_t rowoff = (size_t)tok * HD;
#pragma unroll
                for (int in = 0; in < 4; ++in) {
                    int c = ct * 128 + wc * 64 + in * 16 + rr;
                    float gp = accG[im][in][j] + bgv[in];
                    float sg = 1.f / (1.f + __expf(-gp));
                    float2 tq = __half22float2(tpk[im][in][j >> 1]);
                    float tr = (j & 1) ? tq.y : tq.x;
                    float xv = x[rowoff + c];
                    float yv = sg * tr + (1.f - sg) * xv;
                    atomicAdd(&out[rowoff + c], wgt * yv);
                }
            }
        }
}

extern "C" void kernel_launch(void* const* d_in, const int* in_sizes, int n_in,
                              void* d_out, int out_size, void* d_ws, size_t ws_size,
                              hipStream_t stream)
{
    const float* x   = (const float*)d_in[0];
    const float* Wd  = (const float*)d_in[1];
    const float* bd  = (const float*)d_in[2];
    const float* cen = (const float*)d_in[3];
    const float* Wg  = (const float*)d_in[4];
    const float* bg  = (const float*)d_in[5];
    const float* U   = (const float*)d_in[6];
    const float* V   = (const float*)d_in[7];
    float* out = (float*)d_out;

    char* ws = (char*)d_ws;
    size_t off = 0;
    auto alloc = [&](size_t bytes) { size_t o = off; off = (off + bytes + 255) & ~(size_t)255; return o; };
    float* dT        = (float*)(ws + alloc((size_t)NTOK * CD * 4));
    float* cn        = (float*)(ws + alloc((size_t)NE * CD * 4));
    float* sncn      = (float*)(ws + alloc(NE * 4));
    int*   top_i     = (int*)(ws + alloc((size_t)NTOK * 2 * 4));
    float* top_w     = (float*)(ws + alloc((size_t)NTOK * 2 * 4));
    int*   counts    = (int*)(ws + alloc(NE * 4));
    int*   offsets   = (int*)(ws + alloc((NE + 1) * 4));
    int*   blkstart  = (int*)(ws + alloc((NE + 1) * 4));
    int*   cursor    = (int*)(ws + alloc(NE * 4));
    int*   list_tok  = (int*)(ws + alloc((size_t)NTOK * 2 * 4));
    float* list_w    = (float*)(ws + alloc((size_t)NTOK * 2 * 4));
    u16*   xbf       = (u16*)(ws + alloc((size_t)NTOK * HD * 2));
    u16*   wgT       = (u16*)(ws + alloc((size_t)NE * HD * HD * 2));
    u16*   uT        = (u16*)(ws + alloc((size_t)NE * RD * HD * 2));
    u16*   vT        = (u16*)(ws + alloc((size_t)NE * RD * HD * 2));
    u16*   tbf       = (u16*)(ws + alloc(((size_t)NTOK * 2 + 128) * RD * 2));

    hipMemsetAsync(out, 0, (size_t)out_size * 4, stream);
    hipMemsetAsync(counts, 0, NE * 4, stream);

    centroid_norm_kernel<<<NE, 64, 0, stream>>>(cen, cn, sncn);
    router_gemm_kernel<<<(NTOK / 128) * 4, 256, 0, stream>>>(x, Wd, bd, dT);
    router_score_kernel<<<NTOK / 64, 256, 0, stream>>>(dT, cn, sncn, top_i, top_w, counts);
    scan_kernel<<<1, 64, 0, stream>>>(counts, offsets, blkstart, cursor);
    build_lists_kernel<<<NTOK / 256, 256, 0, stream>>>(top_i, top_w, offsets, cursor, list_tok, list_w);

    cvt_bf16_kernel<<<(NTOK * HD / 4 + 255) / 256, 256, 0, stream>>>(x, xbf, NTOK * HD / 4);
    transpose_cvt_kernel<<<dim3(HD / 32, HD / 32, NE), 256, 0, stream>>>(Wg, wgT, HD, HD);
    transpose_cvt_kernel<<<dim3(RD / 32, HD / 32, NE), 256, 0, stream>>>(U, uT, HD, RD);
    transpose_cvt_kernel<<<dim3(HD / 32, RD / 32, NE), 256, 0, stream>>>(V, vT, RD, HD);

    tproj_kernel<<<MB2, 256, 0, stream>>>(xbf, uT, list_tok, offsets, blkstart, tbf);
    expert_kernel<<<EGRID, 256, 0, stream>>>(xbf, wgT, vT, tbf, x, bg,
                                             list_tok, list_w, offsets, blkstart, out);
}